// Round 2
// baseline (459.322 us; speedup 1.0000x reference)
//
#include <hip/hip_runtime.h>

#define CC 64
#define HH 128
#define WW 128
#define HWS (HH * WW)
#define NG 4

// For one axis: fold {grid_sample 2 corners (weights 1-t, t; zeros padding)} x
// {2x bilinear upsample taps (align_corners=False)} into <=3 consecutive
// source taps of x starting at `base`. `half` selects the quadrant
// (up-index = half*n + corner).
__device__ __forceinline__ void make_taps(float gp, int n, int half, int& base,
                                          float w[3]) {
  w[0] = 0.0f; w[1] = 0.0f; w[2] = 0.0f;
  float f = floorf(gp);
  int x0 = (int)f;
  float t = gp - f;
  base = 0;
#pragma unroll
  for (int k = 0; k < 2; ++k) {
    int xc = x0 + k;
    float cw = k ? t : 1.0f - t;
    if (xc < 0 || xc >= n) cw = 0.0f;      // zeros padding validity
    int xcc = min(max(xc, 0), n - 1);      // safe address (weight is 0 if clipped)
    int u = half * n + xcc;                // index in upsampled axis [0, 2n)
    // upsample source: src = max((u+0.5)/2 - 0.5, 0)
    float src = fmaxf((float)u * 0.5f - 0.25f, 0.0f);
    float sf = floorf(src);
    int i0 = (int)sf;                      // always <= n-1 (src <= n-0.75)
    float tu = src - sf;
    int i1 = min(i0 + 1, n - 1);
    if (k == 0) base = i0;                 // min index across all 4 taps
    w[i0 - base] += cw * (1.0f - tu);
    w[i1 - base] += cw * tu;
  }
}

__global__ __launch_bounds__(256, 4) void dysample_fused(
    const float* __restrict__ x,
    const float* __restrict__ w_off, const float* __restrict__ b_off,
    const float* __restrict__ w_mask, const float* __restrict__ b_mask,
    float* __restrict__ out, int npix) {
  // stage conv weights transposed: wt[c][d], d in [0,12): 0-7 offset, 8-11 mask
  __shared__ float wt[CC * 12];
  for (int idx = threadIdx.x; idx < CC * 12; idx += 256) {
    int c = idx / 12, d = idx - c * 12;
    wt[idx] = (d < 8) ? w_off[d * CC + c] : w_mask[(d - 8) * CC + c];
  }
  __syncthreads();

  int pix = blockIdx.x * 256 + threadIdx.x;
  if (pix >= npix) return;
  int b = pix >> 14;            // / (128*128)
  int ij = pix & (HWS - 1);
  int i = ij >> 7, j = ij & (WW - 1);

  const float* __restrict__ xp = x + (size_t)b * CC * HWS;

  // 1x1 convs: 8 offset channels + 4 mask channels
  float a12[12];
#pragma unroll
  for (int d = 0; d < 12; ++d) a12[d] = (d < 8) ? b_off[d] : b_mask[d - 8];

  for (int c = 0; c < CC; ++c) {
    float xv = xp[c * HWS + ij];
    const float4 w0 = *reinterpret_cast<const float4*>(&wt[c * 12 + 0]);
    const float4 w1 = *reinterpret_cast<const float4*>(&wt[c * 12 + 4]);
    const float4 w2 = *reinterpret_cast<const float4*>(&wt[c * 12 + 8]);
    a12[0]  = fmaf(w0.x, xv, a12[0]);
    a12[1]  = fmaf(w0.y, xv, a12[1]);
    a12[2]  = fmaf(w0.z, xv, a12[2]);
    a12[3]  = fmaf(w0.w, xv, a12[3]);
    a12[4]  = fmaf(w1.x, xv, a12[4]);
    a12[5]  = fmaf(w1.y, xv, a12[5]);
    a12[6]  = fmaf(w1.z, xv, a12[6]);
    a12[7]  = fmaf(w1.w, xv, a12[7]);
    a12[8]  = fmaf(w2.x, xv, a12[8]);
    a12[9]  = fmaf(w2.y, xv, a12[9]);
    a12[10] = fmaf(w2.z, xv, a12[10]);
    a12[11] = fmaf(w2.w, xv, a12[11]);
  }

  // per-group 3x3 stencil geometry (plane offsets + combined weights w/ mask)
  int off9[NG][9];
  float w9[NG][9];
#pragma unroll
  for (int g = 0; g < NG; ++g) {
    int sy = g >> 1, sx = g & 1;
    float mg = 1.0f / (1.0f + __expf(-a12[8 + g]));  // sigmoid
    float gxp = (float)j + a12[2 * g]     - 0.5f;    // pixel-space sample x
    float gyp = (float)i + a12[2 * g + 1] - 0.5f;    // pixel-space sample y
    int cb, rb;
    float wx[3], wy[3];
    make_taps(gxp, WW, sx, cb, wx);
    make_taps(gyp, HH, sy, rb, wy);
#pragma unroll
    for (int dy = 0; dy < 3; ++dy) {
      int r = min(rb + dy, HH - 1) * WW;
#pragma unroll
      for (int dx = 0; dx < 3; ++dx) {
        off9[g][dy * 3 + dx] = r + min(cb + dx, WW - 1);
        w9[g][dy * 3 + dx] = wy[dy] * wx[dx] * mg;
      }
    }
  }

  // channel loop: 4 groups x 9-tap gather-stencil, group-summed
  float* __restrict__ op = out + (size_t)b * CC * HWS + ij;
  for (int c = 0; c < CC; ++c) {
    const float* __restrict__ xc = xp + c * HWS;
    float s = 0.0f;
#pragma unroll
    for (int g = 0; g < NG; ++g) {
#pragma unroll
      for (int k = 0; k < 9; ++k) {
        s = fmaf(w9[g][k], xc[off9[g][k]], s);
      }
    }
    op[c * HWS] = s;
  }
}

extern "C" void kernel_launch(void* const* d_in, const int* in_sizes, int n_in,
                              void* d_out, int out_size, void* d_ws, size_t ws_size,
                              hipStream_t stream) {
  const float* x      = (const float*)d_in[0];
  const float* w_off  = (const float*)d_in[1];
  const float* b_off  = (const float*)d_in[2];
  const float* w_mask = (const float*)d_in[3];
  const float* b_mask = (const float*)d_in[4];
  float* out = (float*)d_out;

  int B = in_sizes[0] / (CC * HWS);
  int npix = B * HWS;
  int nblk = (npix + 255) / 256;
  hipLaunchKernelGGL(dysample_fused, dim3(nblk), dim3(256), 0, stream,
                     x, w_off, b_off, w_mask, b_mask, out, npix);
}